// Round 4
// baseline (127.290 us; speedup 1.0000x reference)
//
#include <hip/hip_runtime.h>

// AttentionGCN on MI355X.
// Math: softmax over axis-of-size-1 == 1 -> h == x (aff_w/cog_w dead).
//   L1: aggregate in 5-dim input space (scatter commutes with W1).
//   L2: apply W2 first, aggregate in 2-dim output space.
// R2: counting-sort into node bins + LDS accumulators (no fp32 global atomics).
// R3: bins 512->256 (2x blocks), u8 dloc, unroll-4 gather chains (int4/uchar4),
//     y padded to stride 8 (float4+float gather) -> 4x less serial latency depth.

#define NPB    256          // nodes per bin
#define BSHIFT 8
#define BINCAP 5120         // mean E/nbins ~4092, sigma ~64 -> +16 sigma headroom
#define MAXBINS 512
#define APT    16           // edges per thread in binning pass
#define ABLK   512          // threads in binning pass

__global__ __launch_bounds__(ABLK) void binA_k(const int* __restrict__ src, const int* __restrict__ dst,
                                               int E, int nbins, int* __restrict__ cursor,
                                               int* __restrict__ bsrc, unsigned char* __restrict__ bdl) {
    __shared__ int hist[MAXBINS];
    __shared__ int gbase[MAXBINS];
    int t = threadIdx.x;
    hist[t] = 0; hist[t + ABLK] = 0;  // MAXBINS == 2*ABLK
    __syncthreads();
    int base = blockIdx.x * (ABLK * APT);
    int s[APT], d[APT];
#pragma unroll
    for (int q = 0; q < APT; ++q) {
        int e = base + q * ABLK + t;
        if (e < E) { s[q] = src[e]; d[q] = dst[e]; atomicAdd(&hist[d[q] >> BSHIFT], 1); }
        else d[q] = -1;
    }
    __syncthreads();
    for (int b = t; b < nbins; b += ABLK) {
        int h = hist[b];
        gbase[b] = h ? atomicAdd(&cursor[b], h) : 0;
        hist[b] = 0;                       // reuse as intra-block cursor
    }
    __syncthreads();
#pragma unroll
    for (int q = 0; q < APT; ++q) {
        if (d[q] >= 0) {
            int b = d[q] >> BSHIFT;
            int pos = gbase[b] + atomicAdd(&hist[b], 1);
            if (pos < BINCAP) {
                bsrc[(size_t)b * BINCAP + pos] = s[q];
                bdl [(size_t)b * BINCAP + pos] = (unsigned char)(d[q] & (NPB - 1));
            }
        }
    }
}

// block b owns nodes [b*NPB, b*NPB+NPB): in-degree in LDS, emit dinv and y8 = dinv*x (stride 8)
__global__ __launch_bounds__(NPB) void bincnt_dinv_y_k(const int* __restrict__ cursor,
                                                       const unsigned char* __restrict__ bdl,
                                                       const float* __restrict__ x,
                                                       float* __restrict__ dinv, float* __restrict__ y8, int n) {
    __shared__ int cnt[NPB];
    int b = blockIdx.x, t = threadIdx.x;
    cnt[t] = 0;
    __syncthreads();
    int m = cursor[b]; if (m > BINCAP) m = BINCAP;
    const unsigned char* dl = bdl + (size_t)b * BINCAP;
    for (int j0 = t * 4; j0 < m; j0 += NPB * 4) {
        if (j0 + 3 < m) {
            uchar4 dv = *(const uchar4*)(dl + j0);
            atomicAdd(&cnt[dv.x], 1); atomicAdd(&cnt[dv.y], 1);
            atomicAdd(&cnt[dv.z], 1); atomicAdd(&cnt[dv.w], 1);
        } else {
            for (int j = j0; j < m; ++j) atomicAdd(&cnt[dl[j]], 1);
        }
    }
    __syncthreads();
    int i = b * NPB + t;
    if (i < n) {
        float di = rsqrtf(1.0f + (float)cnt[t]);   // ref deg = 1 + indegree
        dinv[i] = di;
#pragma unroll
        for (int k = 0; k < 5; ++k) y8[i * 8 + k] = di * x[i * 5 + k];
    }
}

// block b: LDS-accumulate sum_in y[s] for its 256 nodes, then fused node MLP
__global__ __launch_bounds__(NPB) void agg1_mlp_k(const int* __restrict__ cursor,
                                                  const int* __restrict__ bsrc,
                                                  const unsigned char* __restrict__ bdl,
                                                  const float* __restrict__ x, const float* __restrict__ y8,
                                                  const float* __restrict__ dinv,
                                                  const float* __restrict__ W1, const float* __restrict__ b1,
                                                  const float* __restrict__ W2,
                                                  float* __restrict__ g, float* __restrict__ gy, int n) {
    __shared__ float acc[NPB * 5];
    __shared__ float W1s[320], b1s[64], W2s[128];
    int b = blockIdx.x, t = threadIdx.x;
#pragma unroll
    for (int k = 0; k < 5; ++k) acc[t + k * NPB] = 0.f;
    if (t < 64) { b1s[t] = b1[t]; }
    if (t >= 64 && t < 192) W2s[t - 64] = W2[t - 64];
    { int w = t & 63; int grp = t >> 6; // 4 groups of 64 load W1 (320)
      for (int j = grp * 64 + w; j < 320; j += 256) W1s[j] = W1[j]; }
    __syncthreads();
    int m = cursor[b]; if (m > BINCAP) m = BINCAP;
    const int* bs = bsrc + (size_t)b * BINCAP;
    const unsigned char* dl = bdl + (size_t)b * BINCAP;
    for (int j0 = t * 4; j0 < m; j0 += NPB * 4) {
        if (j0 + 3 < m) {
            int4 sv = *(const int4*)(bs + j0);
            uchar4 dv = *(const uchar4*)(dl + j0);
            float4 a0 = *(const float4*)(y8 + (size_t)sv.x * 8); float e0 = y8[(size_t)sv.x * 8 + 4];
            float4 a1 = *(const float4*)(y8 + (size_t)sv.y * 8); float e1 = y8[(size_t)sv.y * 8 + 4];
            float4 a2 = *(const float4*)(y8 + (size_t)sv.z * 8); float e2 = y8[(size_t)sv.z * 8 + 4];
            float4 a3 = *(const float4*)(y8 + (size_t)sv.w * 8); float e3 = y8[(size_t)sv.w * 8 + 4];
            float* p0 = acc + dv.x * 5;
            atomicAdd(p0 + 0, a0.x); atomicAdd(p0 + 1, a0.y); atomicAdd(p0 + 2, a0.z);
            atomicAdd(p0 + 3, a0.w); atomicAdd(p0 + 4, e0);
            float* p1 = acc + dv.y * 5;
            atomicAdd(p1 + 0, a1.x); atomicAdd(p1 + 1, a1.y); atomicAdd(p1 + 2, a1.z);
            atomicAdd(p1 + 3, a1.w); atomicAdd(p1 + 4, e1);
            float* p2 = acc + dv.z * 5;
            atomicAdd(p2 + 0, a2.x); atomicAdd(p2 + 1, a2.y); atomicAdd(p2 + 2, a2.z);
            atomicAdd(p2 + 3, a2.w); atomicAdd(p2 + 4, e2);
            float* p3 = acc + dv.w * 5;
            atomicAdd(p3 + 0, a3.x); atomicAdd(p3 + 1, a3.y); atomicAdd(p3 + 2, a3.z);
            atomicAdd(p3 + 3, a3.w); atomicAdd(p3 + 4, e3);
        } else {
            for (int j = j0; j < m; ++j) {
                int sidx = bs[j];
                float* p = acc + dl[j] * 5;
                const float* ys = y8 + (size_t)sidx * 8;
#pragma unroll
                for (int k = 0; k < 5; ++k) atomicAdd(p + k, ys[k]);
            }
        }
    }
    __syncthreads();
    int i = b * NPB + t;
    if (i >= n) return;
    float di = dinv[i], d2 = di * di;
    float v0 = di * acc[t * 5 + 0] + d2 * x[i * 5 + 0];
    float v1 = di * acc[t * 5 + 1] + d2 * x[i * 5 + 1];
    float v2 = di * acc[t * 5 + 2] + d2 * x[i * 5 + 2];
    float v3 = di * acc[t * 5 + 3] + d2 * x[i * 5 + 3];
    float v4 = di * acc[t * 5 + 4] + d2 * x[i * 5 + 4];
    float g0 = 0.f, g1 = 0.f;
#pragma unroll
    for (int j = 0; j < 64; ++j) {
        float h = b1s[j];
        h = fmaf(v0, W1s[0 * 64 + j], h);
        h = fmaf(v1, W1s[1 * 64 + j], h);
        h = fmaf(v2, W1s[2 * 64 + j], h);
        h = fmaf(v3, W1s[3 * 64 + j], h);
        h = fmaf(v4, W1s[4 * 64 + j], h);
        h = fmaxf(h, 0.f);
        g0 = fmaf(h, W2s[2 * j], g0);
        g1 = fmaf(h, W2s[2 * j + 1], g1);
    }
    g[i * 2] = g0;       g[i * 2 + 1] = g1;
    gy[i * 2] = di * g0; gy[i * 2 + 1] = di * g1;
}

// block b: LDS-accumulate sum_in gy[s], fused bias + log_softmax
__global__ __launch_bounds__(NPB) void agg2_final_k(const int* __restrict__ cursor,
                                                    const int* __restrict__ bsrc,
                                                    const unsigned char* __restrict__ bdl,
                                                    const float* __restrict__ g, const float* __restrict__ gy,
                                                    const float* __restrict__ dinv,
                                                    const float* __restrict__ b2,
                                                    float* __restrict__ out, int n) {
    __shared__ float acc[NPB * 2];
    int b = blockIdx.x, t = threadIdx.x;
    acc[t] = 0.f; acc[t + NPB] = 0.f;
    __syncthreads();
    int m = cursor[b]; if (m > BINCAP) m = BINCAP;
    const int* bs = bsrc + (size_t)b * BINCAP;
    const unsigned char* dl = bdl + (size_t)b * BINCAP;
    for (int j0 = t * 4; j0 < m; j0 += NPB * 4) {
        if (j0 + 3 < m) {
            int4 sv = *(const int4*)(bs + j0);
            uchar4 dv = *(const uchar4*)(dl + j0);
            float2 v0 = *(const float2*)(gy + (size_t)sv.x * 2);
            float2 v1 = *(const float2*)(gy + (size_t)sv.y * 2);
            float2 v2 = *(const float2*)(gy + (size_t)sv.z * 2);
            float2 v3 = *(const float2*)(gy + (size_t)sv.w * 2);
            atomicAdd(&acc[dv.x * 2 + 0], v0.x); atomicAdd(&acc[dv.x * 2 + 1], v0.y);
            atomicAdd(&acc[dv.y * 2 + 0], v1.x); atomicAdd(&acc[dv.y * 2 + 1], v1.y);
            atomicAdd(&acc[dv.z * 2 + 0], v2.x); atomicAdd(&acc[dv.z * 2 + 1], v2.y);
            atomicAdd(&acc[dv.w * 2 + 0], v3.x); atomicAdd(&acc[dv.w * 2 + 1], v3.y);
        } else {
            for (int j = j0; j < m; ++j) {
                int sidx = bs[j];
                int dloc = dl[j];
                atomicAdd(&acc[dloc * 2 + 0], gy[(size_t)sidx * 2]);
                atomicAdd(&acc[dloc * 2 + 1], gy[(size_t)sidx * 2 + 1]);
            }
        }
    }
    __syncthreads();
    int i = b * NPB + t;
    if (i >= n) return;
    float di = dinv[i], d2 = di * di;
    float o0 = di * acc[t * 2 + 0] + d2 * g[i * 2]     + b2[0];
    float o1 = di * acc[t * 2 + 1] + d2 * g[i * 2 + 1] + b2[1];
    float mx = fmaxf(o0, o1);
    float lse = mx + logf(expf(o0 - mx) + expf(o1 - mx));
    out[i * 2]     = o0 - lse;
    out[i * 2 + 1] = o1 - lse;
}

// ---------------- fallback (R1, proven 170us) if ws too small / n too big ------
#define CAP 48
__global__ void fill_k(const int* __restrict__ src, const int* __restrict__ dst,
                       int E, int n, int* __restrict__ cnt, int* __restrict__ bucket) {
    int e = blockIdx.x * blockDim.x + threadIdx.x;
    if (e >= E) return;
    int s = src[e], d = dst[e];
    int slot = atomicAdd(&cnt[d], 1);
    if (slot < CAP) bucket[slot * n + d] = s;
}
__global__ void dinv_y_k(const float* __restrict__ x, const int* __restrict__ cnt,
                         float* __restrict__ dinv, float* __restrict__ y, int n) {
    int i = blockIdx.x * blockDim.x + threadIdx.x;
    if (i >= n) return;
    float di = rsqrtf(1.0f + (float)cnt[i]);
    dinv[i] = di;
#pragma unroll
    for (int k = 0; k < 5; ++k) y[i * 5 + k] = di * x[i * 5 + k];
}
__global__ void gather1_mlp_k(const float* __restrict__ x, const float* __restrict__ y,
                              const float* __restrict__ dinv, const int* __restrict__ cnt,
                              const int* __restrict__ bucket, int n,
                              const float* __restrict__ W1, const float* __restrict__ b1,
                              const float* __restrict__ W2,
                              float* __restrict__ g, float* __restrict__ gy) {
    __shared__ float W1s[320]; __shared__ float b1s[64]; __shared__ float W2s[128];
    int t = threadIdx.x;
    for (int j = t; j < 320; j += blockDim.x) W1s[j] = W1[j];
    if (t < 64) { b1s[t] = b1[t]; W2s[2 * t] = W2[2 * t]; W2s[2 * t + 1] = W2[2 * t + 1]; }
    __syncthreads();
    int i = blockIdx.x * blockDim.x + t;
    if (i >= n) return;
    int c = cnt[i]; if (c > CAP) c = CAP;
    float a0 = 0, a1 = 0, a2 = 0, a3 = 0, a4 = 0;
    for (int j = 0; j < c; ++j) {
        int s = bucket[j * n + i];
        const float* ys = y + s * 5;
        a0 += ys[0]; a1 += ys[1]; a2 += ys[2]; a3 += ys[3]; a4 += ys[4];
    }
    float di = dinv[i], d2 = di * di;
    float v0 = di * a0 + d2 * x[i * 5 + 0], v1 = di * a1 + d2 * x[i * 5 + 1];
    float v2 = di * a2 + d2 * x[i * 5 + 2], v3 = di * a3 + d2 * x[i * 5 + 3];
    float v4 = di * a4 + d2 * x[i * 5 + 4];
    float g0 = 0.f, g1 = 0.f;
#pragma unroll
    for (int j = 0; j < 64; ++j) {
        float h = b1s[j];
        h = fmaf(v0, W1s[j], h); h = fmaf(v1, W1s[64 + j], h); h = fmaf(v2, W1s[128 + j], h);
        h = fmaf(v3, W1s[192 + j], h); h = fmaf(v4, W1s[256 + j], h);
        h = fmaxf(h, 0.f);
        g0 = fmaf(h, W2s[2 * j], g0); g1 = fmaf(h, W2s[2 * j + 1], g1);
    }
    g[i * 2] = g0; g[i * 2 + 1] = g1;
    gy[i * 2] = di * g0; gy[i * 2 + 1] = di * g1;
}
__global__ void gather2_final_k(const float* __restrict__ g, const float* __restrict__ gy,
                                const float* __restrict__ dinv, const int* __restrict__ cnt,
                                const int* __restrict__ bucket, int n,
                                const float* __restrict__ b2, float* __restrict__ out) {
    int i = blockIdx.x * blockDim.x + threadIdx.x;
    if (i >= n) return;
    int c = cnt[i]; if (c > CAP) c = CAP;
    float t0 = 0.f, t1 = 0.f;
    for (int j = 0; j < c; ++j) {
        int s = bucket[j * n + i];
        t0 += gy[s * 2]; t1 += gy[s * 2 + 1];
    }
    float di = dinv[i], d2 = di * di;
    float o0 = di * t0 + d2 * g[i * 2] + b2[0];
    float o1 = di * t1 + d2 * g[i * 2 + 1] + b2[1];
    float mx = fmaxf(o0, o1);
    float lse = mx + logf(expf(o0 - mx) + expf(o1 - mx));
    out[i * 2] = o0 - lse; out[i * 2 + 1] = o1 - lse;
}
// --------------------------------------------------------------------------------

extern "C" void kernel_launch(void* const* d_in, const int* in_sizes, int n_in,
                              void* d_out, int out_size, void* d_ws, size_t ws_size,
                              hipStream_t stream) {
    const float* x  = (const float*)d_in[0];
    const int*   ei = (const int*)d_in[1];
    const float* W1 = (const float*)d_in[4];
    const float* b1 = (const float*)d_in[5];
    const float* W2 = (const float*)d_in[6];
    const float* b2 = (const float*)d_in[7];
    float* out = (float*)d_out;

    const int n = in_sizes[0] / 5;
    const int E = in_sizes[1] / 2;
    const int* src = ei;
    const int* dst = ei + E;

    const int nbins = (n + NPB - 1) >> BSHIFT;
    // layout: cursor[MAXBINS] | bsrc[nbins*BINCAP] int | bdl[nbins*BINCAP] u8 |
    //         dinv[n] | y8[8n] | g[2n] | gy[2n]
    size_t need = (size_t)MAXBINS * 4 + (size_t)nbins * BINCAP * 5 + (size_t)n * (1 + 8 + 2 + 2) * 4;

    if (nbins <= MAXBINS && ws_size >= need) {
        int*   cursor = (int*)d_ws;
        int*   bsrc   = cursor + MAXBINS;
        unsigned char* bdl = (unsigned char*)(bsrc + (size_t)nbins * BINCAP);
        float* dinv = (float*)(bdl + (((size_t)nbins * BINCAP + 15) & ~(size_t)15));
        float* y8   = dinv + n;
        float* g    = y8 + 8 * (size_t)n;
        float* gy   = g + 2 * (size_t)n;

        hipMemsetAsync(cursor, 0, MAXBINS * sizeof(int), stream);
        int ablocks = (E + ABLK * APT - 1) / (ABLK * APT);
        binA_k<<<ablocks, ABLK, 0, stream>>>(src, dst, E, nbins, cursor, bsrc, bdl);
        bincnt_dinv_y_k<<<nbins, NPB, 0, stream>>>(cursor, bdl, x, dinv, y8, n);
        agg1_mlp_k<<<nbins, NPB, 0, stream>>>(cursor, bsrc, bdl, x, y8, dinv, W1, b1, W2, g, gy, n);
        agg2_final_k<<<nbins, NPB, 0, stream>>>(cursor, bsrc, bdl, g, gy, dinv, b2, out, n);
    } else {
        const int BLK = 256;
        const int ngrid = (n + BLK - 1) / BLK;
        const int egrid = (E + BLK - 1) / BLK;
        int*   cnt    = (int*)d_ws;
        int*   bucket = cnt + n;
        float* dinv   = (float*)(bucket + (size_t)CAP * n);
        float* y      = dinv + n;
        float* g      = y + 5 * (size_t)n;
        float* gy     = g + 2 * (size_t)n;
        hipMemsetAsync(cnt, 0, (size_t)n * sizeof(int), stream);
        fill_k<<<egrid, BLK, 0, stream>>>(src, dst, E, n, cnt, bucket);
        dinv_y_k<<<ngrid, BLK, 0, stream>>>(x, cnt, dinv, y, n);
        gather1_mlp_k<<<ngrid, BLK, 0, stream>>>(x, y, dinv, cnt, bucket, n, W1, b1, W2, g, gy);
        gather2_final_k<<<ngrid, BLK, 0, stream>>>(g, gy, dinv, cnt, bucket, n, b2, out);
    }
}

// Round 5
// 75.985 us; speedup vs baseline: 1.6752x; 1.6752x over previous
//
#include <hip/hip_runtime.h>

// AttentionGCN on MI355X.
// Math: softmax over axis-of-size-1 == 1 -> h == x (aff_w/cog_w dead).
//   L1: aggregate in 5-dim input space (scatter commutes with W1).
//   L2: apply W2 first, aggregate in 2-dim output space.
// R2/R3 lesson: divergent LDS atomicAdd ~5cyc/lane-op; 8/edge dominated runtime.
// R4: counting-sort with rank-in-register (1 LDS atomic/edge in binA, 1 in build),
//     full per-node CSR, atomic-free register-accumulating gather kernels.

#define NPB     256         // nodes per bin
#define BSHIFT  8
#define BINCAP  5120        // mean edges/bin ~4092, sigma ~64 -> +16 sigma headroom
#define MAXBINS 512
#define ABLK    256         // binA block threads
#define APT     16          // edges per thread in binA
#define ROUNDS  5           // BINCAP / (256*4)

// ---- pass 1: counting-sort edges into 256-node bins, packed (src<<8)|dloc ----
__global__ __launch_bounds__(ABLK) void binA_k(const int* __restrict__ src, const int* __restrict__ dst,
                                               int E, int nbins, int* __restrict__ cursor,
                                               unsigned int* __restrict__ bpk) {
    __shared__ int hist[MAXBINS];
    __shared__ int gbase[MAXBINS];
    int t = threadIdx.x;
    hist[t] = 0; hist[t + 256] = 0;
    __syncthreads();
    int base = blockIdx.x * (ABLK * APT);
    int s_[APT], d_[APT], r_[APT];
#pragma unroll
    for (int q = 0; q < APT; ++q) {
        int e = base + q * ABLK + t;
        if (e < E) {
            s_[q] = src[e]; d_[q] = dst[e];
            r_[q] = atomicAdd(&hist[d_[q] >> BSHIFT], 1);
        } else d_[q] = -1;
    }
    __syncthreads();
    for (int b = t; b < nbins; b += ABLK) {
        int h = hist[b];
        gbase[b] = h ? atomicAdd(&cursor[b], h) : 0;
    }
    __syncthreads();
#pragma unroll
    for (int q = 0; q < APT; ++q) {
        if (d_[q] >= 0) {
            int b = d_[q] >> BSHIFT;
            int pos = gbase[b] + r_[q];
            if (pos < BINCAP)
                bpk[(size_t)b * BINCAP + pos] = ((unsigned int)s_[q] << 8) | (unsigned int)(d_[q] & (NPB - 1));
        }
    }
}

// ---- pass 2: per bin, build node-sorted CSR + dinv + y8 (one LDS atomic/edge) ----
__global__ __launch_bounds__(NPB) void build_k(const int* __restrict__ cursor,
                                               const unsigned int* __restrict__ bpk,
                                               const float* __restrict__ x,
                                               int* __restrict__ sorted,
                                               int* __restrict__ row_start,
                                               unsigned short* __restrict__ row_cnt,
                                               float* __restrict__ dinv, float* __restrict__ y8, int n) {
    __shared__ int cnt[NPB];
    __shared__ int offs[NPB];
    __shared__ int srt[BINCAP];
    __shared__ int wsum[4];
    int b = blockIdx.x, t = threadIdx.x;
    cnt[t] = 0;
    __syncthreads();
    int m = cursor[b]; if (m > BINCAP) m = BINCAP;
    const unsigned int* pk = bpk + (size_t)b * BINCAP;

    unsigned int pv[ROUNDS][4];
    int rk[ROUNDS][4];
#pragma unroll
    for (int q = 0; q < ROUNDS; ++q) {
        int j0 = q * (NPB * 4) + t * 4;
        if (j0 + 3 < m) {
            uint4 v = *(const uint4*)(pk + j0);
            pv[q][0] = v.x; pv[q][1] = v.y; pv[q][2] = v.z; pv[q][3] = v.w;
            rk[q][0] = atomicAdd(&cnt[v.x & 255u], 1);
            rk[q][1] = atomicAdd(&cnt[v.y & 255u], 1);
            rk[q][2] = atomicAdd(&cnt[v.z & 255u], 1);
            rk[q][3] = atomicAdd(&cnt[v.w & 255u], 1);
        } else {
#pragma unroll
            for (int qq = 0; qq < 4; ++qq) {
                int j = j0 + qq;
                if (j < m) { pv[q][qq] = pk[j]; rk[q][qq] = atomicAdd(&cnt[pv[q][qq] & 255u], 1); }
                else pv[q][qq] = 0xffffffffu;
            }
        }
    }
    __syncthreads();
    // exclusive block scan of cnt -> offs
    int c = cnt[t];
    int lane = t & 63, w = t >> 6;
    int v = c;
#pragma unroll
    for (int dlt = 1; dlt < 64; dlt <<= 1) {
        int u = __shfl_up(v, dlt, 64);
        if (lane >= dlt) v += u;
    }
    if (lane == 63) wsum[w] = v;
    __syncthreads();
    int wo = 0;
#pragma unroll
    for (int k = 0; k < 4; ++k) if (k < w) wo += wsum[k];
    offs[t] = wo + v - c;
    __syncthreads();
    // scatter into LDS at unique positions (no atomics)
#pragma unroll
    for (int q = 0; q < ROUNDS; ++q) {
#pragma unroll
        for (int qq = 0; qq < 4; ++qq) {
            unsigned int p = pv[q][qq];
            if (p != 0xffffffffu) {
                int j0 = q * (NPB * 4) + t * 4 + qq;
                if (j0 < m) srt[offs[p & 255u] + rk[q][qq]] = (int)(p >> 8);
            }
        }
    }
    __syncthreads();
    // coalesced dump of sorted srcs
    int gbase = b * BINCAP;
    for (int j0 = t * 4; j0 + 3 < m; j0 += NPB * 4)
        *(int4*)(sorted + gbase + j0) = *(const int4*)(srt + j0);
    if (t < 4) { // tail (up to 3)
        int start = m & ~3;
        int j = start + t;
        if (j < m) sorted[gbase + j] = srt[j];
    }
    // per-node metadata + dinv + y8
    int i = b * NPB + t;
    if (i < n) {
        row_start[i] = gbase + offs[t];
        row_cnt[i] = (unsigned short)c;
        float di = rsqrtf(1.0f + (float)c);     // ref deg = 1 + indegree
        dinv[i] = di;
#pragma unroll
        for (int k = 0; k < 5; ++k) y8[(size_t)i * 8 + k] = di * x[i * 5 + k];
    }
}

// ---- pass 3: per-node atomic-free aggregate (5-dim) + fused MLP ----
__global__ __launch_bounds__(128) void gath1_mlp_k(const int* __restrict__ sorted,
                                                   const int* __restrict__ row_start,
                                                   const unsigned short* __restrict__ row_cnt,
                                                   const float* __restrict__ x, const float* __restrict__ y8,
                                                   const float* __restrict__ dinv,
                                                   const float* __restrict__ W1, const float* __restrict__ b1,
                                                   const float* __restrict__ W2,
                                                   float* __restrict__ g, float* __restrict__ gy, int n) {
    __shared__ float W1s[320], b1s[64], W2s[128];
    int t = threadIdx.x;
    for (int j = t; j < 320; j += 128) W1s[j] = W1[j];
    if (t < 64) b1s[t] = b1[t];
    if (t < 128) W2s[t] = W2[t];
    __syncthreads();
    int i = blockIdx.x * 128 + t;
    if (i >= n) return;
    int st = row_start[i];
    int c  = row_cnt[i];
    int e  = st + c;
    float a0 = 0.f, a1 = 0.f, a2 = 0.f, a3 = 0.f, a4 = 0.f;
    int j = st;
    for (; j + 3 < e; j += 4) {
        int s0 = sorted[j], s1 = sorted[j + 1], s2 = sorted[j + 2], s3 = sorted[j + 3];
        float4 A0 = *(const float4*)(y8 + (size_t)s0 * 8); float e0 = y8[(size_t)s0 * 8 + 4];
        float4 A1 = *(const float4*)(y8 + (size_t)s1 * 8); float e1 = y8[(size_t)s1 * 8 + 4];
        float4 A2 = *(const float4*)(y8 + (size_t)s2 * 8); float e2 = y8[(size_t)s2 * 8 + 4];
        float4 A3 = *(const float4*)(y8 + (size_t)s3 * 8); float e3 = y8[(size_t)s3 * 8 + 4];
        a0 += A0.x + A1.x + A2.x + A3.x;
        a1 += A0.y + A1.y + A2.y + A3.y;
        a2 += A0.z + A1.z + A2.z + A3.z;
        a3 += A0.w + A1.w + A2.w + A3.w;
        a4 += e0 + e1 + e2 + e3;
    }
    for (; j < e; ++j) {
        int s = sorted[j];
        float4 A = *(const float4*)(y8 + (size_t)s * 8);
        a0 += A.x; a1 += A.y; a2 += A.z; a3 += A.w; a4 += y8[(size_t)s * 8 + 4];
    }
    float di = dinv[i], d2 = di * di;
    float v0 = di * a0 + d2 * x[i * 5 + 0];
    float v1 = di * a1 + d2 * x[i * 5 + 1];
    float v2 = di * a2 + d2 * x[i * 5 + 2];
    float v3 = di * a3 + d2 * x[i * 5 + 3];
    float v4 = di * a4 + d2 * x[i * 5 + 4];
    float g0 = 0.f, g1 = 0.f;
#pragma unroll
    for (int jj = 0; jj < 64; ++jj) {
        float h = b1s[jj];
        h = fmaf(v0, W1s[0 * 64 + jj], h);
        h = fmaf(v1, W1s[1 * 64 + jj], h);
        h = fmaf(v2, W1s[2 * 64 + jj], h);
        h = fmaf(v3, W1s[3 * 64 + jj], h);
        h = fmaf(v4, W1s[4 * 64 + jj], h);
        h = fmaxf(h, 0.f);
        g0 = fmaf(h, W2s[2 * jj], g0);
        g1 = fmaf(h, W2s[2 * jj + 1], g1);
    }
    g[i * 2] = g0;       g[i * 2 + 1] = g1;
    gy[i * 2] = di * g0; gy[i * 2 + 1] = di * g1;
}

// ---- pass 4: per-node atomic-free aggregate (2-dim) + bias + log_softmax ----
__global__ __launch_bounds__(128) void gath2_final_k(const int* __restrict__ sorted,
                                                     const int* __restrict__ row_start,
                                                     const unsigned short* __restrict__ row_cnt,
                                                     const float* __restrict__ g, const float* __restrict__ gy,
                                                     const float* __restrict__ dinv,
                                                     const float* __restrict__ b2,
                                                     float* __restrict__ out, int n) {
    int i = blockIdx.x * 128 + threadIdx.x;
    if (i >= n) return;
    int st = row_start[i];
    int c  = row_cnt[i];
    int e  = st + c;
    float t0 = 0.f, t1 = 0.f;
    int j = st;
    for (; j + 3 < e; j += 4) {
        int s0 = sorted[j], s1 = sorted[j + 1], s2 = sorted[j + 2], s3 = sorted[j + 3];
        float2 v0 = *(const float2*)(gy + (size_t)s0 * 2);
        float2 v1 = *(const float2*)(gy + (size_t)s1 * 2);
        float2 v2 = *(const float2*)(gy + (size_t)s2 * 2);
        float2 v3 = *(const float2*)(gy + (size_t)s3 * 2);
        t0 += v0.x + v1.x + v2.x + v3.x;
        t1 += v0.y + v1.y + v2.y + v3.y;
    }
    for (; j < e; ++j) {
        int s = sorted[j];
        float2 v = *(const float2*)(gy + (size_t)s * 2);
        t0 += v.x; t1 += v.y;
    }
    float di = dinv[i], d2 = di * di;
    float o0 = di * t0 + d2 * g[i * 2]     + b2[0];
    float o1 = di * t1 + d2 * g[i * 2 + 1] + b2[1];
    float mx = fmaxf(o0, o1);
    float lse = mx + logf(expf(o0 - mx) + expf(o1 - mx));
    out[i * 2]     = o0 - lse;
    out[i * 2 + 1] = o1 - lse;
}

// ---------------- fallback (R1, proven) if ws too small / shape unexpected ------
#define CAP 48
__global__ void fill_k(const int* __restrict__ src, const int* __restrict__ dst,
                       int E, int n, int* __restrict__ cnt, int* __restrict__ bucket) {
    int e = blockIdx.x * blockDim.x + threadIdx.x;
    if (e >= E) return;
    int s = src[e], d = dst[e];
    int slot = atomicAdd(&cnt[d], 1);
    if (slot < CAP) bucket[slot * n + d] = s;
}
__global__ void dinv_y_k(const float* __restrict__ x, const int* __restrict__ cnt,
                         float* __restrict__ dinv, float* __restrict__ y, int n) {
    int i = blockIdx.x * blockDim.x + threadIdx.x;
    if (i >= n) return;
    float di = rsqrtf(1.0f + (float)cnt[i]);
    dinv[i] = di;
#pragma unroll
    for (int k = 0; k < 5; ++k) y[i * 5 + k] = di * x[i * 5 + k];
}
__global__ void gather1_mlp_k(const float* __restrict__ x, const float* __restrict__ y,
                              const float* __restrict__ dinv, const int* __restrict__ cnt,
                              const int* __restrict__ bucket, int n,
                              const float* __restrict__ W1, const float* __restrict__ b1,
                              const float* __restrict__ W2,
                              float* __restrict__ g, float* __restrict__ gy) {
    __shared__ float W1s[320]; __shared__ float b1s[64]; __shared__ float W2s[128];
    int t = threadIdx.x;
    for (int j = t; j < 320; j += blockDim.x) W1s[j] = W1[j];
    if (t < 64) { b1s[t] = b1[t]; W2s[2 * t] = W2[2 * t]; W2s[2 * t + 1] = W2[2 * t + 1]; }
    __syncthreads();
    int i = blockIdx.x * blockDim.x + t;
    if (i >= n) return;
    int c = cnt[i]; if (c > CAP) c = CAP;
    float a0 = 0, a1 = 0, a2 = 0, a3 = 0, a4 = 0;
    for (int j = 0; j < c; ++j) {
        int s = bucket[j * n + i];
        const float* ys = y + s * 5;
        a0 += ys[0]; a1 += ys[1]; a2 += ys[2]; a3 += ys[3]; a4 += ys[4];
    }
    float di = dinv[i], d2 = di * di;
    float v0 = di * a0 + d2 * x[i * 5 + 0], v1 = di * a1 + d2 * x[i * 5 + 1];
    float v2 = di * a2 + d2 * x[i * 5 + 2], v3 = di * a3 + d2 * x[i * 5 + 3];
    float v4 = di * a4 + d2 * x[i * 5 + 4];
    float g0 = 0.f, g1 = 0.f;
#pragma unroll
    for (int j = 0; j < 64; ++j) {
        float h = b1s[j];
        h = fmaf(v0, W1s[j], h); h = fmaf(v1, W1s[64 + j], h); h = fmaf(v2, W1s[128 + j], h);
        h = fmaf(v3, W1s[192 + j], h); h = fmaf(v4, W1s[256 + j], h);
        h = fmaxf(h, 0.f);
        g0 = fmaf(h, W2s[2 * j], g0); g1 = fmaf(h, W2s[2 * j + 1], g1);
    }
    g[i * 2] = g0; g[i * 2 + 1] = g1;
    gy[i * 2] = di * g0; gy[i * 2 + 1] = di * g1;
}
__global__ void gather2_final_fb_k(const float* __restrict__ g, const float* __restrict__ gy,
                                   const float* __restrict__ dinv, const int* __restrict__ cnt,
                                   const int* __restrict__ bucket, int n,
                                   const float* __restrict__ b2, float* __restrict__ out) {
    int i = blockIdx.x * blockDim.x + threadIdx.x;
    if (i >= n) return;
    int c = cnt[i]; if (c > CAP) c = CAP;
    float t0 = 0.f, t1 = 0.f;
    for (int j = 0; j < c; ++j) {
        int s = bucket[j * n + i];
        t0 += gy[s * 2]; t1 += gy[s * 2 + 1];
    }
    float di = dinv[i], d2 = di * di;
    float o0 = di * t0 + d2 * g[i * 2] + b2[0];
    float o1 = di * t1 + d2 * g[i * 2 + 1] + b2[1];
    float mx = fmaxf(o0, o1);
    float lse = mx + logf(expf(o0 - mx) + expf(o1 - mx));
    out[i * 2] = o0 - lse; out[i * 2 + 1] = o1 - lse;
}
// --------------------------------------------------------------------------------

extern "C" void kernel_launch(void* const* d_in, const int* in_sizes, int n_in,
                              void* d_out, int out_size, void* d_ws, size_t ws_size,
                              hipStream_t stream) {
    const float* x  = (const float*)d_in[0];
    const int*   ei = (const int*)d_in[1];
    const float* W1 = (const float*)d_in[4];
    const float* b1 = (const float*)d_in[5];
    const float* W2 = (const float*)d_in[6];
    const float* b2 = (const float*)d_in[7];
    float* out = (float*)d_out;

    const int n = in_sizes[0] / 5;
    const int E = in_sizes[1] / 2;
    const int* src = ei;
    const int* dst = ei + E;

    const int nbins = (n + NPB - 1) >> BSHIFT;
    // layout: cursor[MAXBINS] | bpk[nbins*BINCAP] u32 | sorted[nbins*BINCAP] int |
    //         row_start[n] int | row_cnt[n] u16(pad) | dinv[n] | y8[8n] | g[2n] | gy[2n]
    size_t need = (size_t)MAXBINS * 4 + (size_t)nbins * BINCAP * 8 +
                  (size_t)n * (4 + 2 + 4 + 32 + 8 + 8) + 64;

    if (nbins <= MAXBINS && n < (1 << 24) && ws_size >= need) {
        int* cursor = (int*)d_ws;
        unsigned int* bpk = (unsigned int*)(cursor + MAXBINS);
        int* sorted = (int*)(bpk + (size_t)nbins * BINCAP);
        int* row_start = sorted + (size_t)nbins * BINCAP;
        unsigned short* row_cnt = (unsigned short*)(row_start + n);
        float* dinv = (float*)(row_cnt + ((n + 1) & ~1));
        float* y8 = dinv + n;
        float* g  = y8 + 8 * (size_t)n;
        float* gy = g + 2 * (size_t)n;

        hipMemsetAsync(cursor, 0, MAXBINS * sizeof(int), stream);
        int ablocks = (E + ABLK * APT - 1) / (ABLK * APT);
        binA_k<<<ablocks, ABLK, 0, stream>>>(src, dst, E, nbins, cursor, bpk);
        build_k<<<nbins, NPB, 0, stream>>>(cursor, bpk, x, sorted, row_start, row_cnt, dinv, y8, n);
        int g128 = (n + 127) / 128;
        gath1_mlp_k<<<g128, 128, 0, stream>>>(sorted, row_start, row_cnt, x, y8, dinv, W1, b1, W2, g, gy, n);
        gath2_final_k<<<g128, 128, 0, stream>>>(sorted, row_start, row_cnt, g, gy, dinv, b2, out, n);
    } else {
        const int BLK = 256;
        const int ngrid = (n + BLK - 1) / BLK;
        const int egrid = (E + BLK - 1) / BLK;
        int*   cnt    = (int*)d_ws;
        int*   bucket = cnt + n;
        float* dinv   = (float*)(bucket + (size_t)CAP * n);
        float* y      = dinv + n;
        float* g      = y + 5 * (size_t)n;
        float* gy     = g + 2 * (size_t)n;
        hipMemsetAsync(cnt, 0, (size_t)n * sizeof(int), stream);
        fill_k<<<egrid, BLK, 0, stream>>>(src, dst, E, n, cnt, bucket);
        dinv_y_k<<<ngrid, BLK, 0, stream>>>(x, cnt, dinv, y, n);
        gather1_mlp_k<<<ngrid, BLK, 0, stream>>>(x, y, dinv, cnt, bucket, n, W1, b1, W2, g, gy);
        gather2_final_fb_k<<<ngrid, BLK, 0, stream>>>(g, gy, dinv, cnt, bucket, n, b2, out);
    }
}

// Round 6
// 68.321 us; speedup vs baseline: 1.8631x; 1.1122x over previous
//
#include <hip/hip_runtime.h>

// AttentionGCN on MI355X.
// Math: softmax over axis-of-size-1 == 1 -> h == x (aff_w/cog_w dead).
//   L1: aggregate in 5-dim input space (scatter commutes with W1).
//   L2: apply W2 first, aggregate in 2-dim output space.
// R4: counting-sort -> per-node CSR -> atomic-free gathers (127 -> 76us).
// R5: occupancy push. All kernels were at ~1.5 waves/SIMD (391-782 blocks).
//     binA: 512thr/APT8 (3 waves/SIMD); build: 512thr (3/SIMD);
//     gath1/2: 4 lanes per node + shfl reduce (6/SIMD, serial depth 16->4).

#define NPB     256         // nodes per bin
#define BSHIFT  8
#define BINCAP  6144        // mean edges/bin ~4092, sigma ~64 -> +32 sigma headroom
#define MAXBINS 512
#define ABLK    512         // binA block threads
#define APT     8           // edges per thread in binA
#define BBLK    512         // build block threads
#define ROUNDS  3           // BINCAP / (BBLK*4)

// ---- pass 1: counting-sort edges into 256-node bins, packed (src<<8)|dloc ----
__global__ __launch_bounds__(ABLK) void binA_k(const int* __restrict__ src, const int* __restrict__ dst,
                                               int E, int nbins, int* __restrict__ cursor,
                                               unsigned int* __restrict__ bpk) {
    __shared__ int hist[MAXBINS];
    __shared__ int gbase[MAXBINS];
    int t = threadIdx.x;
    hist[t] = 0;                       // MAXBINS == ABLK
    __syncthreads();
    int base = blockIdx.x * (ABLK * APT);
    int s_[APT], d_[APT], r_[APT];
#pragma unroll
    for (int q = 0; q < APT; ++q) {
        int e = base + q * ABLK + t;
        if (e < E) {
            s_[q] = src[e]; d_[q] = dst[e];
            r_[q] = atomicAdd(&hist[d_[q] >> BSHIFT], 1);
        } else d_[q] = -1;
    }
    __syncthreads();
    if (t < nbins) {
        int h = hist[t];
        gbase[t] = h ? atomicAdd(&cursor[t], h) : 0;
    }
    __syncthreads();
#pragma unroll
    for (int q = 0; q < APT; ++q) {
        if (d_[q] >= 0) {
            int b = d_[q] >> BSHIFT;
            int pos = gbase[b] + r_[q];
            if (pos < BINCAP)
                bpk[(size_t)b * BINCAP + pos] = ((unsigned int)s_[q] << 8) | (unsigned int)(d_[q] & (NPB - 1));
        }
    }
}

// ---- pass 2: per bin, build node-sorted CSR + dinv + y8 (one LDS atomic/edge) ----
__global__ __launch_bounds__(BBLK) void build_k(const int* __restrict__ cursor,
                                                const unsigned int* __restrict__ bpk,
                                                const float* __restrict__ x,
                                                int* __restrict__ sorted,
                                                int* __restrict__ row_start,
                                                unsigned short* __restrict__ row_cnt,
                                                float* __restrict__ dinv, float* __restrict__ y8, int n) {
    __shared__ int cnt[NPB];
    __shared__ int offs[NPB];
    __shared__ int srt[BINCAP];
    __shared__ int wsum[4];
    int b = blockIdx.x, t = threadIdx.x;
    if (t < NPB) cnt[t] = 0;
    __syncthreads();
    int m = cursor[b]; if (m > BINCAP) m = BINCAP;
    const unsigned int* pk = bpk + (size_t)b * BINCAP;

    unsigned int pv[ROUNDS][4];
    int rk[ROUNDS][4];
#pragma unroll
    for (int q = 0; q < ROUNDS; ++q) {
        int j0 = q * (BBLK * 4) + t * 4;
        if (j0 + 3 < m) {
            uint4 v = *(const uint4*)(pk + j0);
            pv[q][0] = v.x; pv[q][1] = v.y; pv[q][2] = v.z; pv[q][3] = v.w;
            rk[q][0] = atomicAdd(&cnt[v.x & 255u], 1);
            rk[q][1] = atomicAdd(&cnt[v.y & 255u], 1);
            rk[q][2] = atomicAdd(&cnt[v.z & 255u], 1);
            rk[q][3] = atomicAdd(&cnt[v.w & 255u], 1);
        } else {
#pragma unroll
            for (int qq = 0; qq < 4; ++qq) {
                int j = j0 + qq;
                if (j < m) { pv[q][qq] = pk[j]; rk[q][qq] = atomicAdd(&cnt[pv[q][qq] & 255u], 1); }
                else pv[q][qq] = 0xffffffffu;
            }
        }
    }
    __syncthreads();
    // exclusive block scan of cnt[0..255] -> offs, done by first 256 threads (waves 0-3)
    int c_ = 0, v = 0;
    int lane = t & 63, w = t >> 6;
    if (t < NPB) {
        c_ = cnt[t];
        v = c_;
#pragma unroll
        for (int dlt = 1; dlt < 64; dlt <<= 1) {
            int u = __shfl_up(v, dlt, 64);
            if (lane >= dlt) v += u;
        }
        if (lane == 63) wsum[w] = v;
    }
    __syncthreads();
    if (t < NPB) {
        int wo = 0;
#pragma unroll
        for (int k = 0; k < 4; ++k) if (k < w) wo += wsum[k];
        offs[t] = wo + v - c_;
    }
    __syncthreads();
    // scatter into LDS at unique positions (no atomics)
#pragma unroll
    for (int q = 0; q < ROUNDS; ++q) {
#pragma unroll
        for (int qq = 0; qq < 4; ++qq) {
            unsigned int p = pv[q][qq];
            if (p != 0xffffffffu) {
                int j0 = q * (BBLK * 4) + t * 4 + qq;
                if (j0 < m) srt[offs[p & 255u] + rk[q][qq]] = (int)(p >> 8);
            }
        }
    }
    __syncthreads();
    // coalesced dump of sorted srcs
    int gb = b * BINCAP;
    for (int j0 = t * 4; j0 + 3 < m; j0 += BBLK * 4)
        *(int4*)(sorted + gb + j0) = *(const int4*)(srt + j0);
    if (t < 4) {
        int start = m & ~3;
        int j = start + t;
        if (j < m) sorted[gb + j] = srt[j];
    }
    // per-node metadata + dinv + y8
    int i = b * NPB + t;
    if (t < NPB && i < n) {
        row_start[i] = gb + offs[t];
        row_cnt[i] = (unsigned short)c_;
        float di = rsqrtf(1.0f + (float)c_);    // ref deg = 1 + indegree
        dinv[i] = di;
#pragma unroll
        for (int k = 0; k < 5; ++k) y8[(size_t)i * 8 + k] = di * x[i * 5 + k];
    }
}

// ---- pass 3: 4 lanes per node, atomic-free aggregate (5-dim) + split MLP ----
__global__ __launch_bounds__(256) void gath1_mlp_k(const int* __restrict__ sorted,
                                                   const int* __restrict__ row_start,
                                                   const unsigned short* __restrict__ row_cnt,
                                                   const float* __restrict__ x, const float* __restrict__ y8,
                                                   const float* __restrict__ dinv,
                                                   const float* __restrict__ W1, const float* __restrict__ b1,
                                                   const float* __restrict__ W2,
                                                   float* __restrict__ g, float* __restrict__ gy, int n) {
    __shared__ float W1s[320], b1s[64], W2s[128];
    int t = threadIdx.x;
    { int j = t; if (j < 320) W1s[j] = W1[j]; j = t + 256; if (j < 320) W1s[j] = W1[j]; }
    if (t < 64) b1s[t] = b1[t];
    if (t >= 64 && t < 192) W2s[t - 64] = W2[t - 64];
    __syncthreads();
    int grp = t >> 2, lane = t & 3;
    int i = blockIdx.x * 64 + grp;
    if (i >= n) return;
    int st = row_start[i];
    int e  = st + row_cnt[i];
    float a0 = 0.f, a1 = 0.f, a2 = 0.f, a3 = 0.f, a4 = 0.f;
    for (int j = st + lane; j < e; j += 4) {
        int s = sorted[j];
        float4 A = *(const float4*)(y8 + (size_t)s * 8);
        a0 += A.x; a1 += A.y; a2 += A.z; a3 += A.w;
        a4 += y8[(size_t)s * 8 + 4];
    }
    a0 += __shfl_xor(a0, 1); a0 += __shfl_xor(a0, 2);
    a1 += __shfl_xor(a1, 1); a1 += __shfl_xor(a1, 2);
    a2 += __shfl_xor(a2, 1); a2 += __shfl_xor(a2, 2);
    a3 += __shfl_xor(a3, 1); a3 += __shfl_xor(a3, 2);
    a4 += __shfl_xor(a4, 1); a4 += __shfl_xor(a4, 2);
    float di = dinv[i], d2 = di * di;
    float v0 = di * a0 + d2 * x[i * 5 + 0];
    float v1 = di * a1 + d2 * x[i * 5 + 1];
    float v2 = di * a2 + d2 * x[i * 5 + 2];
    float v3 = di * a3 + d2 * x[i * 5 + 3];
    float v4 = di * a4 + d2 * x[i * 5 + 4];
    float g0 = 0.f, g1 = 0.f;
#pragma unroll
    for (int q = 0; q < 16; ++q) {
        int jj = lane + q * 4;
        float h = b1s[jj];
        h = fmaf(v0, W1s[0 * 64 + jj], h);
        h = fmaf(v1, W1s[1 * 64 + jj], h);
        h = fmaf(v2, W1s[2 * 64 + jj], h);
        h = fmaf(v3, W1s[3 * 64 + jj], h);
        h = fmaf(v4, W1s[4 * 64 + jj], h);
        h = fmaxf(h, 0.f);
        g0 = fmaf(h, W2s[2 * jj], g0);
        g1 = fmaf(h, W2s[2 * jj + 1], g1);
    }
    g0 += __shfl_xor(g0, 1); g0 += __shfl_xor(g0, 2);
    g1 += __shfl_xor(g1, 1); g1 += __shfl_xor(g1, 2);
    if (lane == 0) {
        g[i * 2] = g0;       g[i * 2 + 1] = g1;
        gy[i * 2] = di * g0; gy[i * 2 + 1] = di * g1;
    }
}

// ---- pass 4: 4 lanes per node, aggregate (2-dim) + bias + log_softmax ----
__global__ __launch_bounds__(256) void gath2_final_k(const int* __restrict__ sorted,
                                                     const int* __restrict__ row_start,
                                                     const unsigned short* __restrict__ row_cnt,
                                                     const float* __restrict__ g, const float* __restrict__ gy,
                                                     const float* __restrict__ dinv,
                                                     const float* __restrict__ b2,
                                                     float* __restrict__ out, int n) {
    int t = threadIdx.x;
    int grp = t >> 2, lane = t & 3;
    int i = blockIdx.x * 64 + grp;
    if (i >= n) return;
    int st = row_start[i];
    int e  = st + row_cnt[i];
    float t0 = 0.f, t1 = 0.f;
    for (int j = st + lane; j < e; j += 4) {
        int s = sorted[j];
        float2 v = *(const float2*)(gy + (size_t)s * 2);
        t0 += v.x; t1 += v.y;
    }
    t0 += __shfl_xor(t0, 1); t0 += __shfl_xor(t0, 2);
    t1 += __shfl_xor(t1, 1); t1 += __shfl_xor(t1, 2);
    if (lane == 0) {
        float di = dinv[i], d2 = di * di;
        float o0 = di * t0 + d2 * g[i * 2]     + b2[0];
        float o1 = di * t1 + d2 * g[i * 2 + 1] + b2[1];
        float mx = fmaxf(o0, o1);
        float lse = mx + logf(expf(o0 - mx) + expf(o1 - mx));
        out[i * 2]     = o0 - lse;
        out[i * 2 + 1] = o1 - lse;
    }
}

// ---------------- fallback (R1, proven) if ws too small / shape unexpected ------
#define CAP 48
__global__ void fill_k(const int* __restrict__ src, const int* __restrict__ dst,
                       int E, int n, int* __restrict__ cnt, int* __restrict__ bucket) {
    int e = blockIdx.x * blockDim.x + threadIdx.x;
    if (e >= E) return;
    int s = src[e], d = dst[e];
    int slot = atomicAdd(&cnt[d], 1);
    if (slot < CAP) bucket[slot * n + d] = s;
}
__global__ void dinv_y_k(const float* __restrict__ x, const int* __restrict__ cnt,
                         float* __restrict__ dinv, float* __restrict__ y, int n) {
    int i = blockIdx.x * blockDim.x + threadIdx.x;
    if (i >= n) return;
    float di = rsqrtf(1.0f + (float)cnt[i]);
    dinv[i] = di;
#pragma unroll
    for (int k = 0; k < 5; ++k) y[i * 5 + k] = di * x[i * 5 + k];
}
__global__ void gather1_mlp_k(const float* __restrict__ x, const float* __restrict__ y,
                              const float* __restrict__ dinv, const int* __restrict__ cnt,
                              const int* __restrict__ bucket, int n,
                              const float* __restrict__ W1, const float* __restrict__ b1,
                              const float* __restrict__ W2,
                              float* __restrict__ g, float* __restrict__ gy) {
    __shared__ float W1s[320]; __shared__ float b1s[64]; __shared__ float W2s[128];
    int t = threadIdx.x;
    for (int j = t; j < 320; j += blockDim.x) W1s[j] = W1[j];
    if (t < 64) { b1s[t] = b1[t]; W2s[2 * t] = W2[2 * t]; W2s[2 * t + 1] = W2[2 * t + 1]; }
    __syncthreads();
    int i = blockIdx.x * blockDim.x + t;
    if (i >= n) return;
    int c = cnt[i]; if (c > CAP) c = CAP;
    float a0 = 0, a1 = 0, a2 = 0, a3 = 0, a4 = 0;
    for (int j = 0; j < c; ++j) {
        int s = bucket[j * n + i];
        const float* ys = y + s * 5;
        a0 += ys[0]; a1 += ys[1]; a2 += ys[2]; a3 += ys[3]; a4 += ys[4];
    }
    float di = dinv[i], d2 = di * di;
    float v0 = di * a0 + d2 * x[i * 5 + 0], v1 = di * a1 + d2 * x[i * 5 + 1];
    float v2 = di * a2 + d2 * x[i * 5 + 2], v3 = di * a3 + d2 * x[i * 5 + 3];
    float v4 = di * a4 + d2 * x[i * 5 + 4];
    float g0 = 0.f, g1 = 0.f;
#pragma unroll
    for (int j = 0; j < 64; ++j) {
        float h = b1s[j];
        h = fmaf(v0, W1s[j], h); h = fmaf(v1, W1s[64 + j], h); h = fmaf(v2, W1s[128 + j], h);
        h = fmaf(v3, W1s[192 + j], h); h = fmaf(v4, W1s[256 + j], h);
        h = fmaxf(h, 0.f);
        g0 = fmaf(h, W2s[2 * j], g0); g1 = fmaf(h, W2s[2 * j + 1], g1);
    }
    g[i * 2] = g0; g[i * 2 + 1] = g1;
    gy[i * 2] = di * g0; gy[i * 2 + 1] = di * g1;
}
__global__ void gather2_final_fb_k(const float* __restrict__ g, const float* __restrict__ gy,
                                   const float* __restrict__ dinv, const int* __restrict__ cnt,
                                   const int* __restrict__ bucket, int n,
                                   const float* __restrict__ b2, float* __restrict__ out) {
    int i = blockIdx.x * blockDim.x + threadIdx.x;
    if (i >= n) return;
    int c = cnt[i]; if (c > CAP) c = CAP;
    float t0 = 0.f, t1 = 0.f;
    for (int j = 0; j < c; ++j) {
        int s = bucket[j * n + i];
        t0 += gy[s * 2]; t1 += gy[s * 2 + 1];
    }
    float di = dinv[i], d2 = di * di;
    float o0 = di * t0 + d2 * g[i * 2] + b2[0];
    float o1 = di * t1 + d2 * g[i * 2 + 1] + b2[1];
    float mx = fmaxf(o0, o1);
    float lse = mx + logf(expf(o0 - mx) + expf(o1 - mx));
    out[i * 2] = o0 - lse; out[i * 2 + 1] = o1 - lse;
}
// --------------------------------------------------------------------------------

extern "C" void kernel_launch(void* const* d_in, const int* in_sizes, int n_in,
                              void* d_out, int out_size, void* d_ws, size_t ws_size,
                              hipStream_t stream) {
    const float* x  = (const float*)d_in[0];
    const int*   ei = (const int*)d_in[1];
    const float* W1 = (const float*)d_in[4];
    const float* b1 = (const float*)d_in[5];
    const float* W2 = (const float*)d_in[6];
    const float* b2 = (const float*)d_in[7];
    float* out = (float*)d_out;

    const int n = in_sizes[0] / 5;
    const int E = in_sizes[1] / 2;
    const int* src = ei;
    const int* dst = ei + E;

    const int nbins = (n + NPB - 1) >> BSHIFT;
    // layout: cursor[MAXBINS] | bpk[nbins*BINCAP] u32 | sorted[nbins*BINCAP] int |
    //         row_start[n] int | row_cnt[n] u16(pad) | dinv[n] | y8[8n] | g[2n] | gy[2n]
    size_t need = (size_t)MAXBINS * 4 + (size_t)nbins * BINCAP * 8 +
                  (size_t)n * (4 + 2 + 4 + 32 + 8 + 8) + 64;

    if (nbins <= MAXBINS && n < (1 << 24) && ws_size >= need) {
        int* cursor = (int*)d_ws;
        unsigned int* bpk = (unsigned int*)(cursor + MAXBINS);
        int* sorted = (int*)(bpk + (size_t)nbins * BINCAP);
        int* row_start = sorted + (size_t)nbins * BINCAP;
        unsigned short* row_cnt = (unsigned short*)(row_start + n);
        float* dinv = (float*)(row_cnt + ((n + 1) & ~1));
        float* y8 = dinv + n;
        float* g  = y8 + 8 * (size_t)n;
        float* gy = g + 2 * (size_t)n;

        hipMemsetAsync(cursor, 0, MAXBINS * sizeof(int), stream);
        int ablocks = (E + ABLK * APT - 1) / (ABLK * APT);
        binA_k<<<ablocks, ABLK, 0, stream>>>(src, dst, E, nbins, cursor, bpk);
        build_k<<<nbins, BBLK, 0, stream>>>(cursor, bpk, x, sorted, row_start, row_cnt, dinv, y8, n);
        int g64 = (n + 63) / 64;
        gath1_mlp_k<<<g64, 256, 0, stream>>>(sorted, row_start, row_cnt, x, y8, dinv, W1, b1, W2, g, gy, n);
        gath2_final_k<<<g64, 256, 0, stream>>>(sorted, row_start, row_cnt, g, gy, dinv, b2, out, n);
    } else {
        const int BLK = 256;
        const int ngrid = (n + BLK - 1) / BLK;
        const int egrid = (E + BLK - 1) / BLK;
        int*   cnt    = (int*)d_ws;
        int*   bucket = cnt + n;
        float* dinv   = (float*)(bucket + (size_t)CAP * n);
        float* y      = dinv + n;
        float* g      = y + 5 * (size_t)n;
        float* gy     = g + 2 * (size_t)n;
        hipMemsetAsync(cnt, 0, (size_t)n * sizeof(int), stream);
        fill_k<<<egrid, BLK, 0, stream>>>(src, dst, E, n, cnt, bucket);
        dinv_y_k<<<ngrid, BLK, 0, stream>>>(x, cnt, dinv, y, n);
        gather1_mlp_k<<<ngrid, BLK, 0, stream>>>(x, y, dinv, cnt, bucket, n, W1, b1, W2, g, gy);
        gather2_final_fb_k<<<ngrid, BLK, 0, stream>>>(g, gy, dinv, cnt, bucket, n, b2, out);
    }
}